// Round 5
// baseline (425.383 us; speedup 1.0000x reference)
//
#include <hip/hip_runtime.h>

#define NN 100000
#define EE 1600000
#define GG 1000
#define BN_EPS 1e-5f
#define NB1 391        // ceil(NN/256) scan blocks

// ---------- segment-max via monotonic uint encoding ----------
__device__ __forceinline__ unsigned encf(float f){
  unsigned u = __float_as_uint(f);
  return (u & 0x80000000u) ? ~u : (u | 0x80000000u);
}
__device__ __forceinline__ float dec0(unsigned e){
  unsigned u = (e & 0x80000000u) ? (e & 0x7fffffffu) : ~e;
  float f = __uint_as_float(u);
  return isfinite(f) ? f : 0.0f;   // init-0 sentinel decodes to NaN -> 0 (empty segment)
}
// ---------- bf16 helpers (RNE) ----------
__device__ __forceinline__ unsigned short f2bf(float f){
  unsigned u = __float_as_uint(f);
  u += 0x7FFFu + ((u >> 16) & 1u);
  return (unsigned short)(u >> 16);
}
__device__ __forceinline__ float bf2f(unsigned short s){
  return __uint_as_float(((unsigned)s) << 16);
}

// ---------- CSR build: count -> scan -> finalize -> scatter ----------
__global__ void k_count(const int* __restrict__ ei, const int* __restrict__ ew,
                        int* __restrict__ cnt){
  int e = blockIdx.x*256 + threadIdx.x;
  if (e < EE && ew[e] == 1) atomicAdd(&cnt[ei[EE + e]], 1);
}

__global__ __launch_bounds__(256) void k_scan1(const int* __restrict__ cnt,
    int* __restrict__ loc, int* __restrict__ bsum){
  __shared__ int sm[256];
  const int i = blockIdx.x*256 + threadIdx.x;
  const int v = (i < NN) ? cnt[i] : 0;
  sm[threadIdx.x] = v;
  __syncthreads();
  for (int off = 1; off < 256; off <<= 1){
    int t = (threadIdx.x >= off) ? sm[threadIdx.x - off] : 0;
    __syncthreads();
    sm[threadIdx.x] += t;
    __syncthreads();
  }
  if (i < NN) loc[i] = sm[threadIdx.x] - v;     // exclusive within block
  if (threadIdx.x == 255) bsum[blockIdx.x] = sm[255];
}

__global__ __launch_bounds__(512) void k_scan2(const int* __restrict__ bsum,
    int* __restrict__ boff){
  __shared__ int sm[512];
  const int t = threadIdx.x;
  const int v = (t < NB1) ? bsum[t] : 0;
  sm[t] = v;
  __syncthreads();
  for (int off = 1; off < 512; off <<= 1){
    int x = (t >= off) ? sm[t - off] : 0;
    __syncthreads();
    sm[t] += x;
    __syncthreads();
  }
  if (t <= NB1) boff[t] = sm[t] - v;            // boff[NB1] = total
}

__global__ void k_fin(const int* __restrict__ cnt, const int* __restrict__ loc,
                      const int* __restrict__ boff, float* __restrict__ dinv,
                      int* __restrict__ rowstart, int* __restrict__ fill){
  const int i = blockIdx.x*256 + threadIdx.x;
  if (i < NN){
    int rs = loc[i] + boff[i >> 8];
    rowstart[i] = rs; fill[i] = rs;
    dinv[i] = rsqrtf((float)cnt[i] + 1.0f);     // +1 self loop
  } else if (i == NN){
    rowstart[NN] = boff[NB1];
  }
}

__global__ void k_scatter(const int* __restrict__ ei, const int* __restrict__ ew,
                          int* __restrict__ fill, int* __restrict__ csr){
  int e = blockIdx.x*256 + threadIdx.x;
  if (e < EE && ew[e] == 1){
    int c = ei[EE + e];
    int pos = atomicAdd(&fill[c], 1);
    csr[pos] = ei[e];
  }
}

// ---------- GEMM1: Y1 = x@W1 + b1, accumulate column sum/sumsq ----------
__global__ __launch_bounds__(256) void k_gemm1(const float* __restrict__ x,
    const float* __restrict__ W1, const float* __restrict__ b1,
    float* __restrict__ Y1, float* __restrict__ stats){
  __shared__ float xs[32*132];     // 32 rows x 128, padded
  __shared__ float Ws[128*32];
  __shared__ float red[64];
  const int tid = threadIdx.x;
  for (int j = tid; j < 1024; j += 256) ((float4*)Ws)[j] = ((const float4*)W1)[j];
  const int r = tid >> 3, cg = tid & 7;
  const float4 bv = ((const float4*)b1)[cg];
  float s0=0,s1=0,s2=0,s3=0,q0=0,q1=0,q2=0,q3=0;
  for (int tile = blockIdx.x; tile < 3125; tile += gridDim.x){
    __syncthreads();
    for (int j = tid; j < 1024; j += 256){
      int rr = j >> 5, kk = j & 31;
      *(float4*)&xs[rr*132 + kk*4] = ((const float4*)x)[(size_t)tile*1024 + j];
    }
    __syncthreads();
    float a0=bv.x, a1=bv.y, a2=bv.z, a3=bv.w;
    const float* xr = &xs[r*132];
    const float* wc = &Ws[cg*4];
    #pragma unroll 8
    for (int k = 0; k < 128; k++){
      float xv = xr[k];
      float4 w = *(const float4*)&wc[k*32];
      a0 += xv*w.x; a1 += xv*w.y; a2 += xv*w.z; a3 += xv*w.w;
    }
    float4 o; o.x=a0; o.y=a1; o.z=a2; o.w=a3;
    ((float4*)Y1)[(size_t)(tile*32 + r)*8 + cg] = o;
    s0+=a0; s1+=a1; s2+=a2; s3+=a3;
    q0+=a0*a0; q1+=a1*a1; q2+=a2*a2; q3+=a3*a3;
  }
  __syncthreads();
  if (tid < 64) red[tid] = 0.f;
  __syncthreads();
  atomicAdd(&red[cg*4+0], s0); atomicAdd(&red[cg*4+1], s1);
  atomicAdd(&red[cg*4+2], s2); atomicAdd(&red[cg*4+3], s3);
  atomicAdd(&red[32+cg*4+0], q0); atomicAdd(&red[32+cg*4+1], q1);
  atomicAdd(&red[32+cg*4+2], q2); atomicAdd(&red[32+cg*4+3], q3);
  __syncthreads();
  if (tid < 64) atomicAdd(&stats[tid], red[tid]);
}

// ---------- BN finalize: scale/shift from sums ----------
__global__ void k_stats(float* __restrict__ stats, const float* __restrict__ gamma,
                        const float* __restrict__ beta, int base){
  int c = threadIdx.x;  // 32 threads
  float mean = stats[base + c] * (1.0f/NN);
  float var  = stats[base + 32 + c] * (1.0f/NN) - mean*mean;
  float sc = gamma[c] * rsqrtf(fmaxf(var, 0.0f) + BN_EPS);
  stats[base + 64 + c] = sc;
  stats[base + 96 + c] = beta[c] - mean*sc;
}

// ---------- MLP2: Y2 = relu(bn1(Y1))@W2 + b2, accumulate stats2 ----------
__global__ __launch_bounds__(256) void k_mlp2(const float* __restrict__ Y1,
    const float* __restrict__ W2, const float* __restrict__ b2,
    float* __restrict__ stats, float* __restrict__ Y2){
  __shared__ float hs[32*36];
  __shared__ float Ws[32*32];
  __shared__ float red[64];
  const int tid = threadIdx.x;
  ((float4*)Ws)[tid] = ((const float4*)W2)[tid];
  const int r = tid >> 3, cg = tid & 7;
  const float4 bv = ((const float4*)b2)[cg];
  const float4 sc = ((const float4*)(stats + 64))[cg];
  const float4 sh = ((const float4*)(stats + 96))[cg];
  float s0=0,s1=0,s2=0,s3=0,q0=0,q1=0,q2=0,q3=0;
  for (int tile = blockIdx.x; tile < 3125; tile += gridDim.x){
    __syncthreads();
    {
      float4 v = ((const float4*)Y1)[(size_t)tile*256 + tid];
      v.x = fmaxf(fmaf(v.x, sc.x, sh.x), 0.f);
      v.y = fmaxf(fmaf(v.y, sc.y, sh.y), 0.f);
      v.z = fmaxf(fmaf(v.z, sc.z, sh.z), 0.f);
      v.w = fmaxf(fmaf(v.w, sc.w, sh.w), 0.f);
      *(float4*)&hs[r*36 + cg*4] = v;
    }
    __syncthreads();
    float a0=bv.x, a1=bv.y, a2=bv.z, a3=bv.w;
    const float* hr = &hs[r*36];
    const float* wc = &Ws[cg*4];
    #pragma unroll
    for (int k = 0; k < 32; k++){
      float h = hr[k];
      float4 w = *(const float4*)&wc[k*32];
      a0 += h*w.x; a1 += h*w.y; a2 += h*w.z; a3 += h*w.w;
    }
    float4 o; o.x=a0; o.y=a1; o.z=a2; o.w=a3;
    ((float4*)Y2)[(size_t)(tile*32 + r)*8 + cg] = o;
    s0+=a0; s1+=a1; s2+=a2; s3+=a3;
    q0+=a0*a0; q1+=a1*a1; q2+=a2*a2; q3+=a3*a3;
  }
  __syncthreads();
  if (tid < 64) red[tid] = 0.f;
  __syncthreads();
  atomicAdd(&red[cg*4+0], s0); atomicAdd(&red[cg*4+1], s1);
  atomicAdd(&red[cg*4+2], s2); atomicAdd(&red[cg*4+3], s3);
  atomicAdd(&red[32+cg*4+0], q0); atomicAdd(&red[32+cg*4+1], q1);
  atomicAdd(&red[32+cg*4+2], q2); atomicAdd(&red[32+cg*4+3], q3);
  __syncthreads();
  if (tid < 64) atomicAdd(&stats[128 + tid], red[tid]);
}

// ---------- layer0: h1 = relu(bn2(Y2)); Pool0 <- max(h1@Wl0+bl0); Hg1 = bf16(h1@Wg1) ----------
__global__ __launch_bounds__(256) void k_layer0(const float* __restrict__ Y2,
    const float* __restrict__ stats, const float* __restrict__ Wg1,
    const float* __restrict__ Wl0, const float* __restrict__ bl0,
    const int* __restrict__ batch,
    unsigned short* __restrict__ Hg1, unsigned* __restrict__ Pool0){
  __shared__ float hs[32*36];
  __shared__ float Wg[32*64];
  __shared__ float Wl[320];
  __shared__ float bl[10];
  const int tid = threadIdx.x;
  ((float4*)Wg)[tid]       = ((const float4*)Wg1)[tid];
  ((float4*)Wg)[tid + 256] = ((const float4*)Wg1)[tid + 256];
  for (int j = tid; j < 320; j += 256) Wl[j] = Wl0[j];
  if (tid < 10)  bl[tid] = bl0[tid];
  {
    const int rr = tid >> 3, kk = tid & 7;
    const float4 sc = ((const float4*)(stats + 192))[kk];
    const float4 sh = ((const float4*)(stats + 224))[kk];
    float4 v = ((const float4*)Y2)[(size_t)blockIdx.x*256 + tid];
    v.x = fmaxf(fmaf(v.x, sc.x, sh.x), 0.f);
    v.y = fmaxf(fmaf(v.y, sc.y, sh.y), 0.f);
    v.z = fmaxf(fmaf(v.z, sc.z, sh.z), 0.f);
    v.w = fmaxf(fmaf(v.w, sc.w, sh.w), 0.f);
    *(float4*)&hs[rr*36 + kk*4] = v;
  }
  __syncthreads();
  const int w = tid >> 6, f = tid & 63;
  for (int i = 0; i < 8; i++){
    const int r = w*8 + i;
    const int row = blockIdx.x*32 + r;
    const float* hr = &hs[r*36];
    float acc = 0.f;
    #pragma unroll
    for (int k = 0; k < 32; k++) acc += hr[k]*Wg[k*64 + f];
    Hg1[(size_t)row*64 + f] = f2bf(acc);
    if (f < 10){
      float p = bl[f];
      #pragma unroll
      for (int k = 0; k < 32; k++) p += hr[k]*Wl[k*10 + f];
      atomicMax(&Pool0[batch[row]*10 + f], encf(p));
    }
  }
}

// ---------- gather aggregation (bf16 H): 4 edge-groups x 16 lanes/wave.
//   h = (sum_in H[r]*dinv[r])*dinv[c] + H[c]*dinv[c]^2 + bias ----------
template<bool STORE>
__global__ __launch_bounds__(256) void k_agg(const ushort4* __restrict__ Hb,
    const float* __restrict__ dinv, const int* __restrict__ rowstart,
    const int* __restrict__ csr, const float* __restrict__ bias,
    const int* __restrict__ batch, float* __restrict__ outp,
    unsigned* __restrict__ Pool){
  const int lane = threadIdx.x & 63;
  const int g = lane >> 4;                    // edge group 0..3
  const int l16 = lane & 15;                  // feature quad 0..15
  const int c = blockIdx.x*4 + (threadIdx.x >> 6);
  const int s = rowstart[c], e = rowstart[c+1];
  float a0=0.f, a1=0.f, a2=0.f, a3=0.f;
  for (int j = s + g; j < e; j += 4){
    const int r = csr[j];
    const float dr = dinv[r];
    ushort4 hv = Hb[(size_t)r*16 + l16];
    a0 = fmaf(bf2f(hv.x), dr, a0);
    a1 = fmaf(bf2f(hv.y), dr, a1);
    a2 = fmaf(bf2f(hv.z), dr, a2);
    a3 = fmaf(bf2f(hv.w), dr, a3);
  }
  // reduce across the 4 edge groups (lanes l16, l16+16, l16+32, l16+48)
  a0 += __shfl_xor(a0, 16, 64); a1 += __shfl_xor(a1, 16, 64);
  a2 += __shfl_xor(a2, 16, 64); a3 += __shfl_xor(a3, 16, 64);
  a0 += __shfl_xor(a0, 32, 64); a1 += __shfl_xor(a1, 32, 64);
  a2 += __shfl_xor(a2, 32, 64); a3 += __shfl_xor(a3, 32, 64);
  if (g == 0){
    const float dc = dinv[c];
    const ushort4 hv = Hb[(size_t)c*16 + l16];
    const float4 bv = ((const float4*)bias)[l16];
    const float dcc = dc*dc;
    float h0 = fmaf(a0, dc, fmaf(bf2f(hv.x), dcc, bv.x));
    float h1 = fmaf(a1, dc, fmaf(bf2f(hv.y), dcc, bv.y));
    float h2 = fmaf(a2, dc, fmaf(bf2f(hv.z), dcc, bv.z));
    float h3 = fmaf(a3, dc, fmaf(bf2f(hv.w), dcc, bv.w));
    if (STORE){
      float4 o; o.x=h0; o.y=h1; o.z=h2; o.w=h3;
      ((float4*)outp)[(size_t)c*16 + l16] = o;
    }
    const int b = batch[c];
    atomicMax(&Pool[b*64 + l16*4 + 0], encf(h0));
    atomicMax(&Pool[b*64 + l16*4 + 1], encf(h1));
    atomicMax(&Pool[b*64 + l16*4 + 2], encf(h2));
    atomicMax(&Pool[b*64 + l16*4 + 3], encf(h3));
  }
}

// ---------- layer1 GEMM: Hg2 = bf16(h2 @ Wg2) ----------
__global__ __launch_bounds__(256) void k_layer1(const float* __restrict__ H2,
    const float* __restrict__ Wg2, unsigned short* __restrict__ Hg2){
  __shared__ float as[32*68];
  __shared__ float Wg[64*64];
  const int tid = threadIdx.x;
  #pragma unroll
  for (int j = 0; j < 4; j++) ((float4*)Wg)[tid + j*256] = ((const float4*)Wg2)[tid + j*256];
  #pragma unroll
  for (int j = 0; j < 2; j++){
    int idx = tid + j*256;
    int rr = idx >> 4, kk = idx & 15;
    *(float4*)&as[rr*68 + kk*4] = ((const float4*)H2)[(size_t)blockIdx.x*512 + idx];
  }
  __syncthreads();
  const int w = tid >> 6, f = tid & 63;
  for (int i = 0; i < 8; i++){
    const int r = w*8 + i;
    const float* ar = &as[r*68];
    float acc = 0.f;
    #pragma unroll
    for (int k = 0; k < 64; k++) acc += ar[k]*Wg[k*64 + f];
    Hg2[(size_t)(blockIdx.x*32 + r)*64 + f] = f2bf(acc);
  }
}

// ---------- final: out = P0 + P1@Wl1+bl1 + P2@Wl2+bl2 ----------
__global__ __launch_bounds__(256) void k_final(const unsigned* __restrict__ P0,
    const unsigned* __restrict__ P1, const unsigned* __restrict__ P2,
    const float* __restrict__ Wl1, const float* __restrict__ bl1,
    const float* __restrict__ Wl2, const float* __restrict__ bl2,
    float* __restrict__ out){
  const int t = blockIdx.x*256 + threadIdx.x;
  const int g = t >> 4, c = t & 15;
  if (g >= GG || c >= 10) return;
  float acc = dec0(P0[g*10 + c]) + bl1[c] + bl2[c];
  for (int f = 0; f < 64; f++){
    acc += dec0(P1[g*64 + f]) * Wl1[f*10 + c];
    acc += dec0(P2[g*64 + f]) * Wl2[f*10 + c];
  }
  out[g*10 + c] = acc;
}

extern "C" void kernel_launch(void* const* d_in, const int* in_sizes, int n_in,
                              void* d_out, int out_size, void* d_ws, size_t ws_size,
                              hipStream_t stream){
  const float* x   = (const float*)d_in[0];
  const int*   ei  = (const int*)d_in[1];
  const int*   ew  = (const int*)d_in[2];
  const int*   bat = (const int*)d_in[3];
  const float* W1  = (const float*)d_in[5],  *b1  = (const float*)d_in[6];
  const float* g1  = (const float*)d_in[7],  *bt1 = (const float*)d_in[8];
  const float* W2  = (const float*)d_in[9],  *b2  = (const float*)d_in[10];
  const float* g2  = (const float*)d_in[11], *bt2 = (const float*)d_in[12];
  const float* Wl0 = (const float*)d_in[13], *bl0 = (const float*)d_in[14];
  const float* Wg1 = (const float*)d_in[15], *bg1 = (const float*)d_in[16];
  const float* Wl1 = (const float*)d_in[17], *bl1 = (const float*)d_in[18];
  const float* Wg2 = (const float*)d_in[19], *bg2 = (const float*)d_in[20];
  const float* Wl2 = (const float*)d_in[21], *bl2 = (const float*)d_in[22];

  float* ws = (float*)d_ws;
  // workspace layout (4B elems). Zeroed prefix: cnt | stats | P0 | P1 | P2
  const size_t oCnt   = 0;                         // NN ints
  const size_t oStats = NN;                        // 256
  const size_t oP0    = oStats + 256;              // G*10
  const size_t oP1    = oP0 + (size_t)GG*10;       // G*64
  const size_t oP2    = oP1 + (size_t)GG*64;       // G*64
  const size_t oZEnd  = oP2 + (size_t)GG*64;       // zero prefix end
  const size_t oDinv  = oZEnd;                     // NN
  const size_t oLoc   = oDinv + NN;                // NN
  const size_t oBsum  = oLoc + NN;                 // 512
  const size_t oBoff  = oBsum + 512;               // 512
  const size_t oRS    = oBoff + 512;               // NN+8
  const size_t oFill  = oRS + NN + 8;              // NN
  const size_t oCsr   = oFill + NN;                // EE
  const size_t oA     = oCsr + EE;                 // NN*64 f32 (Y1|Y2 -> H2)
  const size_t oHgb   = oA + (size_t)NN*64;        // NN*32 f32-equiv = NN*64 bf16 (Hg1 -> Hg2)

  int*   cnt   = (int*)(ws + oCnt);
  float* stats = ws + oStats;
  unsigned* P0 = (unsigned*)(ws + oP0);
  unsigned* P1 = (unsigned*)(ws + oP1);
  unsigned* P2 = (unsigned*)(ws + oP2);
  float* dinv  = ws + oDinv;
  int*   loc   = (int*)(ws + oLoc);
  int*   bsum  = (int*)(ws + oBsum);
  int*   boff  = (int*)(ws + oBoff);
  int*   rs    = (int*)(ws + oRS);
  int*   fill  = (int*)(ws + oFill);
  int*   csr   = (int*)(ws + oCsr);
  float* Y1    = ws + oA;
  float* Y2    = ws + oA + (size_t)NN*32;
  float* H2    = ws + oA;                          // reuse after Y1/Y2 consumed
  unsigned short* Hgb = (unsigned short*)(ws + oHgb);  // Hg1, then Hg2

  (void)hipMemsetAsync(d_ws, 0, oZEnd*sizeof(float), stream);

  // CSR build (shared by both GCN layers)
  k_count  <<<EE/256, 256, 0, stream>>>(ei, ew, cnt);
  k_scan1  <<<NB1, 256, 0, stream>>>(cnt, loc, bsum);
  k_scan2  <<<1, 512, 0, stream>>>(bsum, boff);
  k_fin    <<<NB1, 256, 0, stream>>>(cnt, loc, boff, dinv, rs, fill);
  k_scatter<<<EE/256, 256, 0, stream>>>(ei, ew, fill, csr);

  // MLP + heads
  k_gemm1<<<1536, 256, 0, stream>>>(x, W1, b1, Y1, stats);
  k_stats<<<1, 32, 0, stream>>>(stats, g1, bt1, 0);
  k_mlp2 <<<1536, 256, 0, stream>>>(Y1, W2, b2, stats, Y2);
  k_stats<<<1, 32, 0, stream>>>(stats, g2, bt2, 128);
  k_layer0<<<3125, 256, 0, stream>>>(Y2, stats, Wg1, Wl0, bl0, bat, Hgb, P0);
  k_agg<true> <<<NN/4, 256, 0, stream>>>((const ushort4*)Hgb, dinv, rs, csr, bg1, bat, H2, P1);
  k_layer1<<<3125, 256, 0, stream>>>(H2, Wg2, Hgb);
  k_agg<false><<<NN/4, 256, 0, stream>>>((const ushort4*)Hgb, dinv, rs, csr, bg2, bat, nullptr, P2);
  k_final<<<(GG*16 + 255)/256, 256, 0, stream>>>(P0, P1, P2, Wl1, bl1, Wl2, bl2, (float*)d_out);
}

// Round 6
// 343.570 us; speedup vs baseline: 1.2381x; 1.2381x over previous
//
#include <hip/hip_runtime.h>

#define NN 100000
#define EE 1600000
#define GG 1000
#define BN_EPS 1e-5f
#define NB1 391        // ceil(NN/256) scan blocks

// ---------- segment-max via monotonic uint encoding ----------
__device__ __forceinline__ unsigned encf(float f){
  unsigned u = __float_as_uint(f);
  return (u & 0x80000000u) ? ~u : (u | 0x80000000u);
}
__device__ __forceinline__ float dec0(unsigned e){
  unsigned u = (e & 0x80000000u) ? (e & 0x7fffffffu) : ~e;
  float f = __uint_as_float(u);
  return isfinite(f) ? f : 0.0f;   // init-0 sentinel decodes to NaN -> 0 (empty segment)
}
// ---------- bf16 helpers (RNE) ----------
__device__ __forceinline__ unsigned short f2bf(float f){
  unsigned u = __float_as_uint(f);
  u += 0x7FFFu + ((u >> 16) & 1u);
  return (unsigned short)(u >> 16);
}
__device__ __forceinline__ float bf2f(unsigned short s){
  return __uint_as_float(((unsigned)s) << 16);
}

// ---------- CSR build: count -> scan -> finalize -> scatter ----------
__global__ void k_count(const int* __restrict__ ei, const int* __restrict__ ew,
                        int* __restrict__ cnt){
  int e = blockIdx.x*256 + threadIdx.x;
  if (e < EE && ew[e] == 1) atomicAdd(&cnt[ei[EE + e]], 1);
}

__global__ __launch_bounds__(256) void k_scan1(const int* __restrict__ cnt,
    int* __restrict__ loc, int* __restrict__ bsum){
  __shared__ int sm[256];
  const int i = blockIdx.x*256 + threadIdx.x;
  const int v = (i < NN) ? cnt[i] : 0;
  sm[threadIdx.x] = v;
  __syncthreads();
  for (int off = 1; off < 256; off <<= 1){
    int t = (threadIdx.x >= off) ? sm[threadIdx.x - off] : 0;
    __syncthreads();
    sm[threadIdx.x] += t;
    __syncthreads();
  }
  if (i < NN) loc[i] = sm[threadIdx.x] - v;     // exclusive within block
  if (threadIdx.x == 255) bsum[blockIdx.x] = sm[255];
}

__global__ __launch_bounds__(512) void k_scan2(const int* __restrict__ bsum,
    int* __restrict__ boff){
  __shared__ int sm[512];
  const int t = threadIdx.x;
  const int v = (t < NB1) ? bsum[t] : 0;
  sm[t] = v;
  __syncthreads();
  for (int off = 1; off < 512; off <<= 1){
    int x = (t >= off) ? sm[t - off] : 0;
    __syncthreads();
    sm[t] += x;
    __syncthreads();
  }
  if (t <= NB1) boff[t] = sm[t] - v;            // boff[NB1] = total
}

__global__ void k_fin(const int* __restrict__ cnt, const int* __restrict__ loc,
                      const int* __restrict__ boff, float* __restrict__ dinv,
                      int* __restrict__ rowstart, int* __restrict__ fill){
  const int i = blockIdx.x*256 + threadIdx.x;
  if (i < NN){
    int rs = loc[i] + boff[i >> 8];
    rowstart[i] = rs; fill[i] = rs;
    dinv[i] = rsqrtf((float)cnt[i] + 1.0f);     // +1 self loop
  } else if (i == NN){
    rowstart[NN] = boff[NB1];
  }
}

__global__ void k_scatter(const int* __restrict__ ei, const int* __restrict__ ew,
                          int* __restrict__ fill, int* __restrict__ csr){
  int e = blockIdx.x*256 + threadIdx.x;
  if (e < EE && ew[e] == 1){
    int c = ei[EE + e];
    int pos = atomicAdd(&fill[c], 1);
    csr[pos] = ei[e];
  }
}

// ---------- GEMM1: Y1 = x@W1 + b1, accumulate column sum/sumsq ----------
__global__ __launch_bounds__(256) void k_gemm1(const float* __restrict__ x,
    const float* __restrict__ W1, const float* __restrict__ b1,
    float* __restrict__ Y1, float* __restrict__ stats){
  __shared__ float xs[32*132];     // 32 rows x 128, padded
  __shared__ float Ws[128*32];
  __shared__ float red[64];
  const int tid = threadIdx.x;
  for (int j = tid; j < 1024; j += 256) ((float4*)Ws)[j] = ((const float4*)W1)[j];
  const int r = tid >> 3, cg = tid & 7;
  const float4 bv = ((const float4*)b1)[cg];
  float s0=0,s1=0,s2=0,s3=0,q0=0,q1=0,q2=0,q3=0;
  for (int tile = blockIdx.x; tile < 3125; tile += gridDim.x){
    __syncthreads();
    for (int j = tid; j < 1024; j += 256){
      int rr = j >> 5, kk = j & 31;
      *(float4*)&xs[rr*132 + kk*4] = ((const float4*)x)[(size_t)tile*1024 + j];
    }
    __syncthreads();
    float a0=bv.x, a1=bv.y, a2=bv.z, a3=bv.w;
    const float* xr = &xs[r*132];
    const float* wc = &Ws[cg*4];
    #pragma unroll 8
    for (int k = 0; k < 128; k++){
      float xv = xr[k];
      float4 w = *(const float4*)&wc[k*32];
      a0 += xv*w.x; a1 += xv*w.y; a2 += xv*w.z; a3 += xv*w.w;
    }
    float4 o; o.x=a0; o.y=a1; o.z=a2; o.w=a3;
    ((float4*)Y1)[(size_t)(tile*32 + r)*8 + cg] = o;
    s0+=a0; s1+=a1; s2+=a2; s3+=a3;
    q0+=a0*a0; q1+=a1*a1; q2+=a2*a2; q3+=a3*a3;
  }
  __syncthreads();
  if (tid < 64) red[tid] = 0.f;
  __syncthreads();
  atomicAdd(&red[cg*4+0], s0); atomicAdd(&red[cg*4+1], s1);
  atomicAdd(&red[cg*4+2], s2); atomicAdd(&red[cg*4+3], s3);
  atomicAdd(&red[32+cg*4+0], q0); atomicAdd(&red[32+cg*4+1], q1);
  atomicAdd(&red[32+cg*4+2], q2); atomicAdd(&red[32+cg*4+3], q3);
  __syncthreads();
  if (tid < 64) atomicAdd(&stats[tid], red[tid]);
}

// ---------- BN finalize: scale/shift from sums ----------
__global__ void k_stats(float* __restrict__ stats, const float* __restrict__ gamma,
                        const float* __restrict__ beta, int base){
  int c = threadIdx.x;  // 32 threads
  float mean = stats[base + c] * (1.0f/NN);
  float var  = stats[base + 32 + c] * (1.0f/NN) - mean*mean;
  float sc = gamma[c] * rsqrtf(fmaxf(var, 0.0f) + BN_EPS);
  stats[base + 64 + c] = sc;
  stats[base + 96 + c] = beta[c] - mean*sc;
}

// ---------- MLP2: Y2 = relu(bn1(Y1))@W2 + b2, accumulate stats2 ----------
__global__ __launch_bounds__(256) void k_mlp2(const float* __restrict__ Y1,
    const float* __restrict__ W2, const float* __restrict__ b2,
    float* __restrict__ stats, float* __restrict__ Y2){
  __shared__ float hs[32*36];
  __shared__ float Ws[32*32];
  __shared__ float red[64];
  const int tid = threadIdx.x;
  ((float4*)Ws)[tid] = ((const float4*)W2)[tid];
  const int r = tid >> 3, cg = tid & 7;
  const float4 bv = ((const float4*)b2)[cg];
  const float4 sc = ((const float4*)(stats + 64))[cg];
  const float4 sh = ((const float4*)(stats + 96))[cg];
  float s0=0,s1=0,s2=0,s3=0,q0=0,q1=0,q2=0,q3=0;
  for (int tile = blockIdx.x; tile < 3125; tile += gridDim.x){
    __syncthreads();
    {
      float4 v = ((const float4*)Y1)[(size_t)tile*256 + tid];
      v.x = fmaxf(fmaf(v.x, sc.x, sh.x), 0.f);
      v.y = fmaxf(fmaf(v.y, sc.y, sh.y), 0.f);
      v.z = fmaxf(fmaf(v.z, sc.z, sh.z), 0.f);
      v.w = fmaxf(fmaf(v.w, sc.w, sh.w), 0.f);
      *(float4*)&hs[r*36 + cg*4] = v;
    }
    __syncthreads();
    float a0=bv.x, a1=bv.y, a2=bv.z, a3=bv.w;
    const float* hr = &hs[r*36];
    const float* wc = &Ws[cg*4];
    #pragma unroll
    for (int k = 0; k < 32; k++){
      float h = hr[k];
      float4 w = *(const float4*)&wc[k*32];
      a0 += h*w.x; a1 += h*w.y; a2 += h*w.z; a3 += h*w.w;
    }
    float4 o; o.x=a0; o.y=a1; o.z=a2; o.w=a3;
    ((float4*)Y2)[(size_t)(tile*32 + r)*8 + cg] = o;
    s0+=a0; s1+=a1; s2+=a2; s3+=a3;
    q0+=a0*a0; q1+=a1*a1; q2+=a2*a2; q3+=a3*a3;
  }
  __syncthreads();
  if (tid < 64) red[tid] = 0.f;
  __syncthreads();
  atomicAdd(&red[cg*4+0], s0); atomicAdd(&red[cg*4+1], s1);
  atomicAdd(&red[cg*4+2], s2); atomicAdd(&red[cg*4+3], s3);
  atomicAdd(&red[32+cg*4+0], q0); atomicAdd(&red[32+cg*4+1], q1);
  atomicAdd(&red[32+cg*4+2], q2); atomicAdd(&red[32+cg*4+3], q3);
  __syncthreads();
  if (tid < 64) atomicAdd(&stats[128 + tid], red[tid]);
}

// ---------- layer0: h1 = relu(bn2(Y2)); Pool0 <- max(h1@Wl0+bl0); Hg1 = bf16(h1@Wg1) ----------
__global__ __launch_bounds__(256) void k_layer0(const float* __restrict__ Y2,
    const float* __restrict__ stats, const float* __restrict__ Wg1,
    const float* __restrict__ Wl0, const float* __restrict__ bl0,
    const int* __restrict__ batch,
    unsigned short* __restrict__ Hg1, unsigned* __restrict__ Pool0){
  __shared__ float hs[32*36];
  __shared__ float Wg[32*64];
  __shared__ float Wl[320];
  __shared__ float bl[10];
  const int tid = threadIdx.x;
  ((float4*)Wg)[tid]       = ((const float4*)Wg1)[tid];
  ((float4*)Wg)[tid + 256] = ((const float4*)Wg1)[tid + 256];
  for (int j = tid; j < 320; j += 256) Wl[j] = Wl0[j];
  if (tid < 10)  bl[tid] = bl0[tid];
  {
    const int rr = tid >> 3, kk = tid & 7;
    const float4 sc = ((const float4*)(stats + 192))[kk];
    const float4 sh = ((const float4*)(stats + 224))[kk];
    float4 v = ((const float4*)Y2)[(size_t)blockIdx.x*256 + tid];
    v.x = fmaxf(fmaf(v.x, sc.x, sh.x), 0.f);
    v.y = fmaxf(fmaf(v.y, sc.y, sh.y), 0.f);
    v.z = fmaxf(fmaf(v.z, sc.z, sh.z), 0.f);
    v.w = fmaxf(fmaf(v.w, sc.w, sh.w), 0.f);
    *(float4*)&hs[rr*36 + kk*4] = v;
  }
  __syncthreads();
  const int w = tid >> 6, f = tid & 63;
  for (int i = 0; i < 8; i++){
    const int r = w*8 + i;
    const int row = blockIdx.x*32 + r;
    const float* hr = &hs[r*36];
    float acc = 0.f;
    #pragma unroll
    for (int k = 0; k < 32; k++) acc += hr[k]*Wg[k*64 + f];
    Hg1[(size_t)row*64 + f] = f2bf(acc);
    if (f < 10){
      float p = bl[f];
      #pragma unroll
      for (int k = 0; k < 32; k++) p += hr[k]*Wl[k*10 + f];
      atomicMax(&Pool0[batch[row]*10 + f], encf(p));
    }
  }
}

// ---------- gather aggregation (bf16 H, lane-per-feature):
//   h = (sum_in H[r]*dinv[r])*dinv[c] + H[c]*dinv[c]^2 + bias
//   pool: LDS-combine 4 nodes/block (batch sorted) -> 1 wave-wide atomicMax ----------
template<bool STORE>
__global__ __launch_bounds__(256) void k_agg(const unsigned short* __restrict__ Hb,
    const float* __restrict__ dinv, const int* __restrict__ rowstart,
    const int* __restrict__ csr, const float* __restrict__ bias,
    const int* __restrict__ batch, float* __restrict__ outp,
    unsigned* __restrict__ Pool){
  __shared__ float sm[4][64];
  __shared__ int sb[4];
  const int w = threadIdx.x >> 6, f = threadIdx.x & 63;
  const int c = blockIdx.x*4 + w;
  const int s = rowstart[c], e = rowstart[c+1];
  float acc = 0.f;
  int j = s;
  for (; j + 3 < e; j += 4){
    const int r0 = csr[j], r1 = csr[j+1], r2 = csr[j+2], r3 = csr[j+3];
    const float d0 = dinv[r0], d1 = dinv[r1], d2 = dinv[r2], d3 = dinv[r3];
    const float h0 = bf2f(Hb[(size_t)r0*64 + f]);
    const float h1 = bf2f(Hb[(size_t)r1*64 + f]);
    const float h2 = bf2f(Hb[(size_t)r2*64 + f]);
    const float h3 = bf2f(Hb[(size_t)r3*64 + f]);
    acc = fmaf(h0, d0, acc); acc = fmaf(h1, d1, acc);
    acc = fmaf(h2, d2, acc); acc = fmaf(h3, d3, acc);
  }
  for (; j < e; j++){
    const int r = csr[j];
    acc = fmaf(bf2f(Hb[(size_t)r*64 + f]), dinv[r], acc);
  }
  const float dc = dinv[c];
  float h = fmaf(acc, dc, bf2f(Hb[(size_t)c*64 + f])*dc*dc) + bias[f];
  if (STORE) outp[(size_t)c*64 + f] = h;
  sm[w][f] = h;
  if (f == 0) sb[w] = batch[c];
  __syncthreads();
  if (w == 0){
    const int b0 = sb[0], b1 = sb[1], b2 = sb[2], b3 = sb[3];
    if (b0 == b3){   // batch sorted: ends equal => all 4 equal
      float m = fmaxf(fmaxf(sm[0][f], sm[1][f]), fmaxf(sm[2][f], sm[3][f]));
      atomicMax(&Pool[b0*64 + f], encf(m));
    } else {
      atomicMax(&Pool[b0*64 + f], encf(sm[0][f]));
      atomicMax(&Pool[b1*64 + f], encf(sm[1][f]));
      atomicMax(&Pool[b2*64 + f], encf(sm[2][f]));
      atomicMax(&Pool[b3*64 + f], encf(sm[3][f]));
    }
  }
}

// ---------- layer1 GEMM: Hg2 = bf16(h2 @ Wg2) ----------
__global__ __launch_bounds__(256) void k_layer1(const float* __restrict__ H2,
    const float* __restrict__ Wg2, unsigned short* __restrict__ Hg2){
  __shared__ float as[32*68];
  __shared__ float Wg[64*64];
  const int tid = threadIdx.x;
  #pragma unroll
  for (int j = 0; j < 4; j++) ((float4*)Wg)[tid + j*256] = ((const float4*)Wg2)[tid + j*256];
  #pragma unroll
  for (int j = 0; j < 2; j++){
    int idx = tid + j*256;
    int rr = idx >> 4, kk = idx & 15;
    *(float4*)&as[rr*68 + kk*4] = ((const float4*)H2)[(size_t)blockIdx.x*512 + idx];
  }
  __syncthreads();
  const int w = tid >> 6, f = tid & 63;
  for (int i = 0; i < 8; i++){
    const int r = w*8 + i;
    const float* ar = &as[r*68];
    float acc = 0.f;
    #pragma unroll
    for (int k = 0; k < 64; k++) acc += ar[k]*Wg[k*64 + f];
    Hg2[(size_t)(blockIdx.x*32 + r)*64 + f] = f2bf(acc);
  }
}

// ---------- final: out = P0 + P1@Wl1+bl1 + P2@Wl2+bl2 ----------
__global__ __launch_bounds__(256) void k_final(const unsigned* __restrict__ P0,
    const unsigned* __restrict__ P1, const unsigned* __restrict__ P2,
    const float* __restrict__ Wl1, const float* __restrict__ bl1,
    const float* __restrict__ Wl2, const float* __restrict__ bl2,
    float* __restrict__ out){
  const int t = blockIdx.x*256 + threadIdx.x;
  const int g = t >> 4, c = t & 15;
  if (g >= GG || c >= 10) return;
  float acc = dec0(P0[g*10 + c]) + bl1[c] + bl2[c];
  for (int f = 0; f < 64; f++){
    acc += dec0(P1[g*64 + f]) * Wl1[f*10 + c];
    acc += dec0(P2[g*64 + f]) * Wl2[f*10 + c];
  }
  out[g*10 + c] = acc;
}

extern "C" void kernel_launch(void* const* d_in, const int* in_sizes, int n_in,
                              void* d_out, int out_size, void* d_ws, size_t ws_size,
                              hipStream_t stream){
  const float* x   = (const float*)d_in[0];
  const int*   ei  = (const int*)d_in[1];
  const int*   ew  = (const int*)d_in[2];
  const int*   bat = (const int*)d_in[3];
  const float* W1  = (const float*)d_in[5],  *b1  = (const float*)d_in[6];
  const float* g1  = (const float*)d_in[7],  *bt1 = (const float*)d_in[8];
  const float* W2  = (const float*)d_in[9],  *b2  = (const float*)d_in[10];
  const float* g2  = (const float*)d_in[11], *bt2 = (const float*)d_in[12];
  const float* Wl0 = (const float*)d_in[13], *bl0 = (const float*)d_in[14];
  const float* Wg1 = (const float*)d_in[15], *bg1 = (const float*)d_in[16];
  const float* Wl1 = (const float*)d_in[17], *bl1 = (const float*)d_in[18];
  const float* Wg2 = (const float*)d_in[19], *bg2 = (const float*)d_in[20];
  const float* Wl2 = (const float*)d_in[21], *bl2 = (const float*)d_in[22];

  float* ws = (float*)d_ws;
  // workspace layout (4B elems). Zeroed prefix: cnt | stats | P0 | P1 | P2
  const size_t oCnt   = 0;                         // NN ints
  const size_t oStats = NN;                        // 256
  const size_t oP0    = oStats + 256;              // G*10
  const size_t oP1    = oP0 + (size_t)GG*10;       // G*64
  const size_t oP2    = oP1 + (size_t)GG*64;       // G*64
  const size_t oZEnd  = oP2 + (size_t)GG*64;       // zero prefix end
  const size_t oDinv  = oZEnd;                     // NN
  const size_t oLoc   = oDinv + NN;                // NN
  const size_t oBsum  = oLoc + NN;                 // 512
  const size_t oBoff  = oBsum + 512;               // 512
  const size_t oRS    = oBoff + 512;               // NN+8
  const size_t oFill  = oRS + NN + 8;              // NN
  const size_t oCsr   = oFill + NN;                // EE
  const size_t oA     = oCsr + EE;                 // NN*64 f32 (Y1|Y2 -> H2)
  const size_t oHgb   = oA + (size_t)NN*64;        // NN*64 bf16 (Hg1 -> Hg2)

  int*   cnt   = (int*)(ws + oCnt);
  float* stats = ws + oStats;
  unsigned* P0 = (unsigned*)(ws + oP0);
  unsigned* P1 = (unsigned*)(ws + oP1);
  unsigned* P2 = (unsigned*)(ws + oP2);
  float* dinv  = ws + oDinv;
  int*   loc   = (int*)(ws + oLoc);
  int*   bsum  = (int*)(ws + oBsum);
  int*   boff  = (int*)(ws + oBoff);
  int*   rs    = (int*)(ws + oRS);
  int*   fill  = (int*)(ws + oFill);
  int*   csr   = (int*)(ws + oCsr);
  float* Y1    = ws + oA;
  float* Y2    = ws + oA + (size_t)NN*32;
  float* H2    = ws + oA;                          // reuse after Y1/Y2 consumed
  unsigned short* Hgb = (unsigned short*)(ws + oHgb);  // Hg1, then Hg2

  (void)hipMemsetAsync(d_ws, 0, oZEnd*sizeof(float), stream);

  // CSR build (shared by both GCN layers)
  k_count  <<<EE/256, 256, 0, stream>>>(ei, ew, cnt);
  k_scan1  <<<NB1, 256, 0, stream>>>(cnt, loc, bsum);
  k_scan2  <<<1, 512, 0, stream>>>(bsum, boff);
  k_fin    <<<NB1, 256, 0, stream>>>(cnt, loc, boff, dinv, rs, fill);
  k_scatter<<<EE/256, 256, 0, stream>>>(ei, ew, fill, csr);

  // MLP + heads
  k_gemm1<<<1536, 256, 0, stream>>>(x, W1, b1, Y1, stats);
  k_stats<<<1, 32, 0, stream>>>(stats, g1, bt1, 0);
  k_mlp2 <<<1536, 256, 0, stream>>>(Y1, W2, b2, stats, Y2);
  k_stats<<<1, 32, 0, stream>>>(stats, g2, bt2, 128);
  k_layer0<<<3125, 256, 0, stream>>>(Y2, stats, Wg1, Wl0, bl0, bat, Hgb, P0);
  k_agg<true> <<<NN/4, 256, 0, stream>>>(Hgb, dinv, rs, csr, bg1, bat, H2, P1);
  k_layer1<<<3125, 256, 0, stream>>>(H2, Wg2, Hgb);
  k_agg<false><<<NN/4, 256, 0, stream>>>(Hgb, dinv, rs, csr, bg2, bat, nullptr, P2);
  k_final<<<(GG*16 + 255)/256, 256, 0, stream>>>(P0, P1, P2, Wl1, bl1, Wl2, bl2, (float*)d_out);
}

// Round 7
// 338.431 us; speedup vs baseline: 1.2569x; 1.0152x over previous
//
#include <hip/hip_runtime.h>

#define NN 100000
#define EE 1600000
#define GG 1000
#define BN_EPS 1e-5f
#define NB1 391        // ceil(NN/256) scan blocks

// ---------- segment-max via monotonic uint encoding ----------
__device__ __forceinline__ unsigned encf(float f){
  unsigned u = __float_as_uint(f);
  return (u & 0x80000000u) ? ~u : (u | 0x80000000u);
}
__device__ __forceinline__ float dec0(unsigned e){
  unsigned u = (e & 0x80000000u) ? (e & 0x7fffffffu) : ~e;
  float f = __uint_as_float(u);
  return isfinite(f) ? f : 0.0f;   // init-0 sentinel decodes to NaN -> 0 (empty segment)
}
// ---------- bf16 helpers (RNE) ----------
__device__ __forceinline__ unsigned short f2bf(float f){
  unsigned u = __float_as_uint(f);
  u += 0x7FFFu + ((u >> 16) & 1u);
  return (unsigned short)(u >> 16);
}
__device__ __forceinline__ float bf2f(unsigned short s){
  return __uint_as_float(((unsigned)s) << 16);
}

// ---------- CSR build: count -> scan -> finalize -> scatter ----------
__global__ void k_count(const int* __restrict__ ei, const int* __restrict__ ew,
                        int* __restrict__ cnt){
  int e = blockIdx.x*256 + threadIdx.x;
  if (e < EE && ew[e] == 1) atomicAdd(&cnt[ei[EE + e]], 1);
}

__global__ __launch_bounds__(256) void k_scan1(const int* __restrict__ cnt,
    int* __restrict__ loc, int* __restrict__ bsum){
  __shared__ int sm[256];
  const int i = blockIdx.x*256 + threadIdx.x;
  const int v = (i < NN) ? cnt[i] : 0;
  sm[threadIdx.x] = v;
  __syncthreads();
  for (int off = 1; off < 256; off <<= 1){
    int t = (threadIdx.x >= off) ? sm[threadIdx.x - off] : 0;
    __syncthreads();
    sm[threadIdx.x] += t;
    __syncthreads();
  }
  if (i < NN) loc[i] = sm[threadIdx.x] - v;     // exclusive within block
  if (threadIdx.x == 255) bsum[blockIdx.x] = sm[255];
}

__global__ __launch_bounds__(512) void k_scan2(const int* __restrict__ bsum,
    int* __restrict__ boff){
  __shared__ int sm[512];
  const int t = threadIdx.x;
  const int v = (t < NB1) ? bsum[t] : 0;
  sm[t] = v;
  __syncthreads();
  for (int off = 1; off < 512; off <<= 1){
    int x = (t >= off) ? sm[t - off] : 0;
    __syncthreads();
    sm[t] += x;
    __syncthreads();
  }
  if (t <= NB1) boff[t] = sm[t] - v;            // boff[NB1] = total
}

__global__ void k_fin(const int* __restrict__ cnt, const int* __restrict__ loc,
                      const int* __restrict__ boff, float* __restrict__ dinv,
                      int* __restrict__ rowstart, int* __restrict__ fill){
  const int i = blockIdx.x*256 + threadIdx.x;
  if (i < NN){
    int rs = loc[i] + boff[i >> 8];
    rowstart[i] = rs; fill[i] = rs;
    dinv[i] = rsqrtf((float)cnt[i] + 1.0f);     // +1 self loop
  } else if (i == NN){
    rowstart[NN] = boff[NB1];
  }
}

__global__ void k_scatter(const int* __restrict__ ei, const int* __restrict__ ew,
                          int* __restrict__ fill, int* __restrict__ csr){
  int e = blockIdx.x*256 + threadIdx.x;
  if (e < EE && ew[e] == 1){
    int c = ei[EE + e];
    int pos = atomicAdd(&fill[c], 1);
    csr[pos] = ei[e];
  }
}

// ---------- GEMM1: Y1 = x@W1 + b1, accumulate column sum/sumsq ----------
__global__ __launch_bounds__(256) void k_gemm1(const float* __restrict__ x,
    const float* __restrict__ W1, const float* __restrict__ b1,
    float* __restrict__ Y1, float* __restrict__ stats){
  __shared__ float xs[32*132];     // 32 rows x 128, padded
  __shared__ float Ws[128*32];
  __shared__ float red[64];
  const int tid = threadIdx.x;
  for (int j = tid; j < 1024; j += 256) ((float4*)Ws)[j] = ((const float4*)W1)[j];
  const int r = tid >> 3, cg = tid & 7;
  const float4 bv = ((const float4*)b1)[cg];
  float s0=0,s1=0,s2=0,s3=0,q0=0,q1=0,q2=0,q3=0;
  for (int tile = blockIdx.x; tile < 3125; tile += gridDim.x){
    __syncthreads();
    for (int j = tid; j < 1024; j += 256){
      int rr = j >> 5, kk = j & 31;
      *(float4*)&xs[rr*132 + kk*4] = ((const float4*)x)[(size_t)tile*1024 + j];
    }
    __syncthreads();
    float a0=bv.x, a1=bv.y, a2=bv.z, a3=bv.w;
    const float* xr = &xs[r*132];
    const float* wc = &Ws[cg*4];
    #pragma unroll 8
    for (int k = 0; k < 128; k++){
      float xv = xr[k];
      float4 w = *(const float4*)&wc[k*32];
      a0 += xv*w.x; a1 += xv*w.y; a2 += xv*w.z; a3 += xv*w.w;
    }
    float4 o; o.x=a0; o.y=a1; o.z=a2; o.w=a3;
    ((float4*)Y1)[(size_t)(tile*32 + r)*8 + cg] = o;
    s0+=a0; s1+=a1; s2+=a2; s3+=a3;
    q0+=a0*a0; q1+=a1*a1; q2+=a2*a2; q3+=a3*a3;
  }
  __syncthreads();
  if (tid < 64) red[tid] = 0.f;
  __syncthreads();
  atomicAdd(&red[cg*4+0], s0); atomicAdd(&red[cg*4+1], s1);
  atomicAdd(&red[cg*4+2], s2); atomicAdd(&red[cg*4+3], s3);
  atomicAdd(&red[32+cg*4+0], q0); atomicAdd(&red[32+cg*4+1], q1);
  atomicAdd(&red[32+cg*4+2], q2); atomicAdd(&red[32+cg*4+3], q3);
  __syncthreads();
  if (tid < 64) atomicAdd(&stats[tid], red[tid]);
}

// ---------- MLP2: Y2 = relu(bn1(Y1))@W2 + b2 (BN finalize inlined), accumulate stats2 ----------
__global__ __launch_bounds__(256) void k_mlp2(const float* __restrict__ Y1,
    const float* __restrict__ W2, const float* __restrict__ b2,
    const float* __restrict__ g1, const float* __restrict__ bt1,
    float* __restrict__ stats, float* __restrict__ Y2){
  __shared__ float hs[32*36];
  __shared__ float Ws[32*32];
  __shared__ float red[64];
  __shared__ float scs[32], shs[32];
  const int tid = threadIdx.x;
  ((float4*)Ws)[tid] = ((const float4*)W2)[tid];
  if (tid < 32){
    float mean = stats[tid] * (1.0f/NN);
    float var  = stats[32 + tid] * (1.0f/NN) - mean*mean;
    float s = g1[tid] * rsqrtf(fmaxf(var, 0.0f) + BN_EPS);
    scs[tid] = s; shs[tid] = bt1[tid] - mean*s;
  }
  __syncthreads();
  const int r = tid >> 3, cg = tid & 7;
  const float4 bv = ((const float4*)b2)[cg];
  const float4 sc = *(const float4*)&scs[cg*4];
  const float4 sh = *(const float4*)&shs[cg*4];
  float s0=0,s1=0,s2=0,s3=0,q0=0,q1=0,q2=0,q3=0;
  for (int tile = blockIdx.x; tile < 3125; tile += gridDim.x){
    __syncthreads();
    {
      float4 v = ((const float4*)Y1)[(size_t)tile*256 + tid];
      v.x = fmaxf(fmaf(v.x, sc.x, sh.x), 0.f);
      v.y = fmaxf(fmaf(v.y, sc.y, sh.y), 0.f);
      v.z = fmaxf(fmaf(v.z, sc.z, sh.z), 0.f);
      v.w = fmaxf(fmaf(v.w, sc.w, sh.w), 0.f);
      *(float4*)&hs[r*36 + cg*4] = v;
    }
    __syncthreads();
    float a0=bv.x, a1=bv.y, a2=bv.z, a3=bv.w;
    const float* hr = &hs[r*36];
    const float* wc = &Ws[cg*4];
    #pragma unroll
    for (int k = 0; k < 32; k++){
      float h = hr[k];
      float4 w = *(const float4*)&wc[k*32];
      a0 += h*w.x; a1 += h*w.y; a2 += h*w.z; a3 += h*w.w;
    }
    float4 o; o.x=a0; o.y=a1; o.z=a2; o.w=a3;
    ((float4*)Y2)[(size_t)(tile*32 + r)*8 + cg] = o;
    s0+=a0; s1+=a1; s2+=a2; s3+=a3;
    q0+=a0*a0; q1+=a1*a1; q2+=a2*a2; q3+=a3*a3;
  }
  __syncthreads();
  if (tid < 64) red[tid] = 0.f;
  __syncthreads();
  atomicAdd(&red[cg*4+0], s0); atomicAdd(&red[cg*4+1], s1);
  atomicAdd(&red[cg*4+2], s2); atomicAdd(&red[cg*4+3], s3);
  atomicAdd(&red[32+cg*4+0], q0); atomicAdd(&red[32+cg*4+1], q1);
  atomicAdd(&red[32+cg*4+2], q2); atomicAdd(&red[32+cg*4+3], q3);
  __syncthreads();
  if (tid < 64) atomicAdd(&stats[128 + tid], red[tid]);
}

// ---------- layer0: h1 = relu(bn2(Y2)) (BN inlined); Pool0 <- max(h1@Wl0+bl0);
//            Hs1 = bf16((h1@Wg1)*dinv) ----------
__global__ __launch_bounds__(256) void k_layer0(const float* __restrict__ Y2,
    const float* __restrict__ stats, const float* __restrict__ g2,
    const float* __restrict__ bt2, const float* __restrict__ Wg1,
    const float* __restrict__ Wl0, const float* __restrict__ bl0,
    const float* __restrict__ dinv, const int* __restrict__ batch,
    unsigned short* __restrict__ Hs1, unsigned* __restrict__ Pool0){
  __shared__ float hs[32*36];
  __shared__ float Wg[32*64];
  __shared__ float Wl[320];
  __shared__ float bl[10];
  __shared__ float scs[32], shs[32];
  const int tid = threadIdx.x;
  ((float4*)Wg)[tid]       = ((const float4*)Wg1)[tid];
  ((float4*)Wg)[tid + 256] = ((const float4*)Wg1)[tid + 256];
  for (int j = tid; j < 320; j += 256) Wl[j] = Wl0[j];
  if (tid < 10)  bl[tid] = bl0[tid];
  if (tid < 32){
    float mean = stats[128 + tid] * (1.0f/NN);
    float var  = stats[160 + tid] * (1.0f/NN) - mean*mean;
    float s = g2[tid] * rsqrtf(fmaxf(var, 0.0f) + BN_EPS);
    scs[tid] = s; shs[tid] = bt2[tid] - mean*s;
  }
  __syncthreads();
  {
    const int rr = tid >> 3, kk = tid & 7;
    const float4 sc = *(const float4*)&scs[kk*4];
    const float4 sh = *(const float4*)&shs[kk*4];
    float4 v = ((const float4*)Y2)[(size_t)blockIdx.x*256 + tid];
    v.x = fmaxf(fmaf(v.x, sc.x, sh.x), 0.f);
    v.y = fmaxf(fmaf(v.y, sc.y, sh.y), 0.f);
    v.z = fmaxf(fmaf(v.z, sc.z, sh.z), 0.f);
    v.w = fmaxf(fmaf(v.w, sc.w, sh.w), 0.f);
    *(float4*)&hs[rr*36 + kk*4] = v;
  }
  __syncthreads();
  const int w = tid >> 6, f = tid & 63;
  for (int i = 0; i < 8; i++){
    const int r = w*8 + i;
    const int row = blockIdx.x*32 + r;
    const float* hr = &hs[r*36];
    float acc = 0.f;
    #pragma unroll
    for (int k = 0; k < 32; k++) acc += hr[k]*Wg[k*64 + f];
    Hs1[(size_t)row*64 + f] = f2bf(acc * dinv[row]);
    if (f < 10){
      float p = bl[f];
      #pragma unroll
      for (int k = 0; k < 32; k++) p += hr[k]*Wl[k*10 + f];
      atomicMax(&Pool0[batch[row]*10 + f], encf(p));
    }
  }
}

// ---------- gather aggregation on pre-scaled bf16 Hs (Hs = H*dinv):
//   h = dc*(sum_in Hs[r] + Hs[c]) + bias
//   pool: LDS-combine 4 nodes/block (batch sorted) -> 1 wave-wide atomicMax
//   GEMM=true: also Hs2out[c] = bf16((h_row @ Wg2) * dc)  [fused layer-1 GEMM] ----------
template<bool GEMM>
__global__ __launch_bounds__(256) void k_agg(const unsigned short* __restrict__ Hs,
    const float* __restrict__ dinv, const int* __restrict__ rowstart,
    const int* __restrict__ csr, const float* __restrict__ bias,
    const int* __restrict__ batch, const float* __restrict__ Wg2,
    unsigned short* __restrict__ Hs2out, unsigned* __restrict__ Pool){
  __shared__ float sm[4][64];
  __shared__ int sb[4];
  __shared__ float WgL[GEMM ? 64*64 : 4];
  const int tid = threadIdx.x;
  if (GEMM){
    #pragma unroll
    for (int j = 0; j < 4; j++)
      ((float4*)WgL)[tid + j*256] = ((const float4*)Wg2)[tid + j*256];
  }
  const int w = tid >> 6, f = tid & 63;
  const int c = blockIdx.x*4 + w;
  const int s = rowstart[c], e = rowstart[c+1];
  float acc = 0.f;
  int j = s;
  for (; j + 3 < e; j += 4){
    const int r0 = csr[j], r1 = csr[j+1], r2 = csr[j+2], r3 = csr[j+3];
    acc += bf2f(Hs[(size_t)r0*64 + f]);
    acc += bf2f(Hs[(size_t)r1*64 + f]);
    acc += bf2f(Hs[(size_t)r2*64 + f]);
    acc += bf2f(Hs[(size_t)r3*64 + f]);
  }
  for (; j < e; j++) acc += bf2f(Hs[(size_t)csr[j]*64 + f]);
  const float dc = dinv[c];
  const float h = fmaf(acc + bf2f(Hs[(size_t)c*64 + f]), dc, bias[f]);
  sm[w][f] = h;
  if (f == 0) sb[w] = batch[c];
  __syncthreads();
  if (w == 0){
    const int b0 = sb[0], b1 = sb[1], b2 = sb[2], b3 = sb[3];
    if (b0 == b3){   // batch sorted: ends equal => all 4 equal
      float m = fmaxf(fmaxf(sm[0][f], sm[1][f]), fmaxf(sm[2][f], sm[3][f]));
      atomicMax(&Pool[b0*64 + f], encf(m));
    } else {
      atomicMax(&Pool[b0*64 + f], encf(sm[0][f]));
      atomicMax(&Pool[b1*64 + f], encf(sm[1][f]));
      atomicMax(&Pool[b2*64 + f], encf(sm[2][f]));
      atomicMax(&Pool[b3*64 + f], encf(sm[3][f]));
    }
  }
  if (GEMM){
    float ga = 0.f;
    const float* hr = sm[w];
    #pragma unroll 16
    for (int k = 0; k < 64; k++) ga = fmaf(hr[k], WgL[k*64 + f], ga);
    Hs2out[(size_t)c*64 + f] = f2bf(ga * dc);
  }
}

// ---------- final: out = P0 + P1@Wl1+bl1 + P2@Wl2+bl2 ----------
__global__ __launch_bounds__(256) void k_final(const unsigned* __restrict__ P0,
    const unsigned* __restrict__ P1, const unsigned* __restrict__ P2,
    const float* __restrict__ Wl1, const float* __restrict__ bl1,
    const float* __restrict__ Wl2, const float* __restrict__ bl2,
    float* __restrict__ out){
  const int t = blockIdx.x*256 + threadIdx.x;
  const int g = t >> 4, c = t & 15;
  if (g >= GG || c >= 10) return;
  float acc = dec0(P0[g*10 + c]) + bl1[c] + bl2[c];
  for (int f = 0; f < 64; f++){
    acc += dec0(P1[g*64 + f]) * Wl1[f*10 + c];
    acc += dec0(P2[g*64 + f]) * Wl2[f*10 + c];
  }
  out[g*10 + c] = acc;
}

extern "C" void kernel_launch(void* const* d_in, const int* in_sizes, int n_in,
                              void* d_out, int out_size, void* d_ws, size_t ws_size,
                              hipStream_t stream){
  const float* x   = (const float*)d_in[0];
  const int*   ei  = (const int*)d_in[1];
  const int*   ew  = (const int*)d_in[2];
  const int*   bat = (const int*)d_in[3];
  const float* W1  = (const float*)d_in[5],  *b1  = (const float*)d_in[6];
  const float* g1  = (const float*)d_in[7],  *bt1 = (const float*)d_in[8];
  const float* W2  = (const float*)d_in[9],  *b2  = (const float*)d_in[10];
  const float* g2  = (const float*)d_in[11], *bt2 = (const float*)d_in[12];
  const float* Wl0 = (const float*)d_in[13], *bl0 = (const float*)d_in[14];
  const float* Wg1 = (const float*)d_in[15], *bg1 = (const float*)d_in[16];
  const float* Wl1 = (const float*)d_in[17], *bl1 = (const float*)d_in[18];
  const float* Wg2 = (const float*)d_in[19], *bg2 = (const float*)d_in[20];
  const float* Wl2 = (const float*)d_in[21], *bl2 = (const float*)d_in[22];

  float* ws = (float*)d_ws;
  // workspace layout (4B elems). Zeroed prefix: cnt | stats | P0 | P1 | P2
  const size_t oCnt   = 0;                         // NN ints
  const size_t oStats = NN;                        // 256
  const size_t oP0    = oStats + 256;              // G*10
  const size_t oP1    = oP0 + (size_t)GG*10;       // G*64
  const size_t oP2    = oP1 + (size_t)GG*64;       // G*64
  const size_t oZEnd  = oP2 + (size_t)GG*64;       // zero prefix end
  const size_t oDinv  = oZEnd;                     // NN
  const size_t oLoc   = oDinv + NN;                // NN
  const size_t oBsum  = oLoc + NN;                 // 512
  const size_t oBoff  = oBsum + 512;               // 512
  const size_t oRS    = oBoff + 512;               // NN+8
  const size_t oFill  = oRS + NN + 8;              // NN
  const size_t oCsr   = oFill + NN;                // EE
  const size_t oA     = oCsr + EE;                 // NN*64 f32 (Y1|Y2), tail reused: Hs2 aliases Y1 half
  const size_t oHs1   = oA + (size_t)NN*64;        // NN*64 bf16 = NN*32 f32-equiv

  int*   cnt   = (int*)(ws + oCnt);
  float* stats = ws + oStats;
  unsigned* P0 = (unsigned*)(ws + oP0);
  unsigned* P1 = (unsigned*)(ws + oP1);
  unsigned* P2 = (unsigned*)(ws + oP2);
  float* dinv  = ws + oDinv;
  int*   loc   = (int*)(ws + oLoc);
  int*   bsum  = (int*)(ws + oBsum);
  int*   boff  = (int*)(ws + oBoff);
  int*   rs    = (int*)(ws + oRS);
  int*   fill  = (int*)(ws + oFill);
  int*   csr   = (int*)(ws + oCsr);
  float* Y1    = ws + oA;
  float* Y2    = ws + oA + (size_t)NN*32;
  unsigned short* Hs2 = (unsigned short*)(ws + oA);   // reuse Y1 region after consumed
  unsigned short* Hs1 = (unsigned short*)(ws + oHs1);

  (void)hipMemsetAsync(d_ws, 0, oZEnd*sizeof(float), stream);

  // CSR build (shared by both GCN layers)
  k_count  <<<EE/256, 256, 0, stream>>>(ei, ew, cnt);
  k_scan1  <<<NB1, 256, 0, stream>>>(cnt, loc, bsum);
  k_scan2  <<<1, 512, 0, stream>>>(bsum, boff);
  k_fin    <<<NB1, 256, 0, stream>>>(cnt, loc, boff, dinv, rs, fill);
  k_scatter<<<EE/256, 256, 0, stream>>>(ei, ew, fill, csr);

  // MLP + heads
  k_gemm1<<<1536, 256, 0, stream>>>(x, W1, b1, Y1, stats);
  k_mlp2 <<<1536, 256, 0, stream>>>(Y1, W2, b2, g1, bt1, stats, Y2);
  k_layer0<<<3125, 256, 0, stream>>>(Y2, stats, g2, bt2, Wg1, Wl0, bl0, dinv, bat, Hs1, P0);
  k_agg<true> <<<NN/4, 256, 0, stream>>>(Hs1, dinv, rs, csr, bg1, bat, Wg2, Hs2, P1);
  k_agg<false><<<NN/4, 256, 0, stream>>>(Hs2, dinv, rs, csr, bg2, bat, nullptr, nullptr, P2);
  k_final<<<(GG*16 + 255)/256, 256, 0, stream>>>(P0, P1, P2, Wl1, bl1, Wl2, bl2, (float*)d_out);
}

// Round 8
// 336.789 us; speedup vs baseline: 1.2631x; 1.0049x over previous
//
#include <hip/hip_runtime.h>

#define NN 100000
#define EE 1600000
#define GG 1000
#define BN_EPS 1e-5f
#define NB1 391        // ceil(NN/256) scan blocks

// ---------- segment-max via monotonic uint encoding ----------
__device__ __forceinline__ unsigned encf(float f){
  unsigned u = __float_as_uint(f);
  return (u & 0x80000000u) ? ~u : (u | 0x80000000u);
}
__device__ __forceinline__ float dec0(unsigned e){
  unsigned u = (e & 0x80000000u) ? (e & 0x7fffffffu) : ~e;
  float f = __uint_as_float(u);
  return isfinite(f) ? f : 0.0f;   // init-0 sentinel decodes to NaN -> 0 (empty segment)
}
// ---------- bf16 helpers (RNE) ----------
__device__ __forceinline__ unsigned short f2bf(float f){
  unsigned u = __float_as_uint(f);
  u += 0x7FFFu + ((u >> 16) & 1u);
  return (unsigned short)(u >> 16);
}
__device__ __forceinline__ float bf2f(unsigned short s){
  return __uint_as_float(((unsigned)s) << 16);
}

// ---------- CSR build: count -> scan -> finalize -> scatter ----------
__global__ void k_count(const int* __restrict__ ei, const int* __restrict__ ew,
                        int* __restrict__ cnt){
  int e = blockIdx.x*256 + threadIdx.x;
  if (e < EE && ew[e] == 1) atomicAdd(&cnt[ei[EE + e]], 1);
}

__global__ __launch_bounds__(256) void k_scan1(const int* __restrict__ cnt,
    int* __restrict__ loc, int* __restrict__ bsum){
  __shared__ int sm[256];
  const int i = blockIdx.x*256 + threadIdx.x;
  const int v = (i < NN) ? cnt[i] : 0;
  sm[threadIdx.x] = v;
  __syncthreads();
  for (int off = 1; off < 256; off <<= 1){
    int t = (threadIdx.x >= off) ? sm[threadIdx.x - off] : 0;
    __syncthreads();
    sm[threadIdx.x] += t;
    __syncthreads();
  }
  if (i < NN) loc[i] = sm[threadIdx.x] - v;     // exclusive within block
  if (threadIdx.x == 255) bsum[blockIdx.x] = sm[255];
}

__global__ __launch_bounds__(512) void k_scan2(const int* __restrict__ bsum,
    int* __restrict__ boff){
  __shared__ int sm[512];
  const int t = threadIdx.x;
  const int v = (t < NB1) ? bsum[t] : 0;
  sm[t] = v;
  __syncthreads();
  for (int off = 1; off < 512; off <<= 1){
    int x = (t >= off) ? sm[t - off] : 0;
    __syncthreads();
    sm[t] += x;
    __syncthreads();
  }
  if (t <= NB1) boff[t] = sm[t] - v;            // boff[NB1] = total
}

__global__ void k_fin(const int* __restrict__ cnt, const int* __restrict__ loc,
                      const int* __restrict__ boff, float* __restrict__ dinv,
                      int* __restrict__ rowstart, int* __restrict__ fill){
  const int i = blockIdx.x*256 + threadIdx.x;
  if (i < NN){
    int rs = loc[i] + boff[i >> 8];
    rowstart[i] = rs; fill[i] = rs;
    dinv[i] = rsqrtf((float)cnt[i] + 1.0f);     // +1 self loop
  } else if (i == NN){
    rowstart[NN] = boff[NB1];
  }
}

__global__ void k_scatter(const int* __restrict__ ei, const int* __restrict__ ew,
                          int* __restrict__ fill, int* __restrict__ csr){
  int e = blockIdx.x*256 + threadIdx.x;
  if (e < EE && ew[e] == 1){
    int c = ei[EE + e];
    int pos = atomicAdd(&fill[c], 1);
    csr[pos] = ei[e];
  }
}

// ---------- GEMM1: Y1 = x@W1 + b1, accumulate column sum/sumsq ----------
__global__ __launch_bounds__(256) void k_gemm1(const float* __restrict__ x,
    const float* __restrict__ W1, const float* __restrict__ b1,
    float* __restrict__ Y1, float* __restrict__ stats){
  __shared__ float xs[32*132];     // 32 rows x 128, padded
  __shared__ float Ws[128*32];
  __shared__ float red[64];
  const int tid = threadIdx.x;
  for (int j = tid; j < 1024; j += 256) ((float4*)Ws)[j] = ((const float4*)W1)[j];
  const int r = tid >> 3, cg = tid & 7;
  const float4 bv = ((const float4*)b1)[cg];
  float s0=0,s1=0,s2=0,s3=0,q0=0,q1=0,q2=0,q3=0;
  for (int tile = blockIdx.x; tile < 3125; tile += gridDim.x){
    __syncthreads();
    for (int j = tid; j < 1024; j += 256){
      int rr = j >> 5, kk = j & 31;
      *(float4*)&xs[rr*132 + kk*4] = ((const float4*)x)[(size_t)tile*1024 + j];
    }
    __syncthreads();
    float a0=bv.x, a1=bv.y, a2=bv.z, a3=bv.w;
    const float* xr = &xs[r*132];
    const float* wc = &Ws[cg*4];
    #pragma unroll 8
    for (int k = 0; k < 128; k++){
      float xv = xr[k];
      float4 w = *(const float4*)&wc[k*32];
      a0 += xv*w.x; a1 += xv*w.y; a2 += xv*w.z; a3 += xv*w.w;
    }
    float4 o; o.x=a0; o.y=a1; o.z=a2; o.w=a3;
    ((float4*)Y1)[(size_t)(tile*32 + r)*8 + cg] = o;
    s0+=a0; s1+=a1; s2+=a2; s3+=a3;
    q0+=a0*a0; q1+=a1*a1; q2+=a2*a2; q3+=a3*a3;
  }
  __syncthreads();
  if (tid < 64) red[tid] = 0.f;
  __syncthreads();
  atomicAdd(&red[cg*4+0], s0); atomicAdd(&red[cg*4+1], s1);
  atomicAdd(&red[cg*4+2], s2); atomicAdd(&red[cg*4+3], s3);
  atomicAdd(&red[32+cg*4+0], q0); atomicAdd(&red[32+cg*4+1], q1);
  atomicAdd(&red[32+cg*4+2], q2); atomicAdd(&red[32+cg*4+3], q3);
  __syncthreads();
  if (tid < 64) atomicAdd(&stats[tid], red[tid]);
}

// ---------- MLP2: Y2 = relu(bn1(Y1))@W2 + b2 (BN finalize inlined), accumulate stats2 ----------
__global__ __launch_bounds__(256) void k_mlp2(const float* __restrict__ Y1,
    const float* __restrict__ W2, const float* __restrict__ b2,
    const float* __restrict__ g1, const float* __restrict__ bt1,
    float* __restrict__ stats, float* __restrict__ Y2){
  __shared__ float hs[32*36];
  __shared__ float Ws[32*32];
  __shared__ float red[64];
  __shared__ float scs[32], shs[32];
  const int tid = threadIdx.x;
  ((float4*)Ws)[tid] = ((const float4*)W2)[tid];
  if (tid < 32){
    float mean = stats[tid] * (1.0f/NN);
    float var  = stats[32 + tid] * (1.0f/NN) - mean*mean;
    float s = g1[tid] * rsqrtf(fmaxf(var, 0.0f) + BN_EPS);
    scs[tid] = s; shs[tid] = bt1[tid] - mean*s;
  }
  __syncthreads();
  const int r = tid >> 3, cg = tid & 7;
  const float4 bv = ((const float4*)b2)[cg];
  const float4 sc = *(const float4*)&scs[cg*4];
  const float4 sh = *(const float4*)&shs[cg*4];
  float s0=0,s1=0,s2=0,s3=0,q0=0,q1=0,q2=0,q3=0;
  for (int tile = blockIdx.x; tile < 3125; tile += gridDim.x){
    __syncthreads();
    {
      float4 v = ((const float4*)Y1)[(size_t)tile*256 + tid];
      v.x = fmaxf(fmaf(v.x, sc.x, sh.x), 0.f);
      v.y = fmaxf(fmaf(v.y, sc.y, sh.y), 0.f);
      v.z = fmaxf(fmaf(v.z, sc.z, sh.z), 0.f);
      v.w = fmaxf(fmaf(v.w, sc.w, sh.w), 0.f);
      *(float4*)&hs[r*36 + cg*4] = v;
    }
    __syncthreads();
    float a0=bv.x, a1=bv.y, a2=bv.z, a3=bv.w;
    const float* hr = &hs[r*36];
    const float* wc = &Ws[cg*4];
    #pragma unroll
    for (int k = 0; k < 32; k++){
      float h = hr[k];
      float4 w = *(const float4*)&wc[k*32];
      a0 += h*w.x; a1 += h*w.y; a2 += h*w.z; a3 += h*w.w;
    }
    float4 o; o.x=a0; o.y=a1; o.z=a2; o.w=a3;
    ((float4*)Y2)[(size_t)(tile*32 + r)*8 + cg] = o;
    s0+=a0; s1+=a1; s2+=a2; s3+=a3;
    q0+=a0*a0; q1+=a1*a1; q2+=a2*a2; q3+=a3*a3;
  }
  __syncthreads();
  if (tid < 64) red[tid] = 0.f;
  __syncthreads();
  atomicAdd(&red[cg*4+0], s0); atomicAdd(&red[cg*4+1], s1);
  atomicAdd(&red[cg*4+2], s2); atomicAdd(&red[cg*4+3], s3);
  atomicAdd(&red[32+cg*4+0], q0); atomicAdd(&red[32+cg*4+1], q1);
  atomicAdd(&red[32+cg*4+2], q2); atomicAdd(&red[32+cg*4+3], q3);
  __syncthreads();
  if (tid < 64) atomicAdd(&stats[128 + tid], red[tid]);
}

// ---------- layer0: h1 = relu(bn2(Y2)) (BN inlined); Pool0 <- max(h1@Wl0+bl0);
//            Hs1 = bf16((h1@Wg1)*dinv) ----------
__global__ __launch_bounds__(256) void k_layer0(const float* __restrict__ Y2,
    const float* __restrict__ stats, const float* __restrict__ g2,
    const float* __restrict__ bt2, const float* __restrict__ Wg1,
    const float* __restrict__ Wl0, const float* __restrict__ bl0,
    const float* __restrict__ dinv, const int* __restrict__ batch,
    unsigned short* __restrict__ Hs1, unsigned* __restrict__ Pool0){
  __shared__ float hs[32*36];
  __shared__ float Wg[32*64];
  __shared__ float Wl[320];
  __shared__ float bl[10];
  __shared__ float scs[32], shs[32];
  const int tid = threadIdx.x;
  ((float4*)Wg)[tid]       = ((const float4*)Wg1)[tid];
  ((float4*)Wg)[tid + 256] = ((const float4*)Wg1)[tid + 256];
  for (int j = tid; j < 320; j += 256) Wl[j] = Wl0[j];
  if (tid < 10)  bl[tid] = bl0[tid];
  if (tid < 32){
    float mean = stats[128 + tid] * (1.0f/NN);
    float var  = stats[160 + tid] * (1.0f/NN) - mean*mean;
    float s = g2[tid] * rsqrtf(fmaxf(var, 0.0f) + BN_EPS);
    scs[tid] = s; shs[tid] = bt2[tid] - mean*s;
  }
  __syncthreads();
  {
    const int rr = tid >> 3, kk = tid & 7;
    const float4 sc = *(const float4*)&scs[kk*4];
    const float4 sh = *(const float4*)&shs[kk*4];
    float4 v = ((const float4*)Y2)[(size_t)blockIdx.x*256 + tid];
    v.x = fmaxf(fmaf(v.x, sc.x, sh.x), 0.f);
    v.y = fmaxf(fmaf(v.y, sc.y, sh.y), 0.f);
    v.z = fmaxf(fmaf(v.z, sc.z, sh.z), 0.f);
    v.w = fmaxf(fmaf(v.w, sc.w, sh.w), 0.f);
    *(float4*)&hs[rr*36 + kk*4] = v;
  }
  __syncthreads();
  const int w = tid >> 6, f = tid & 63;
  for (int i = 0; i < 8; i++){
    const int r = w*8 + i;
    const int row = blockIdx.x*32 + r;
    const float* hr = &hs[r*36];
    float acc = 0.f;
    #pragma unroll
    for (int k = 0; k < 32; k++) acc += hr[k]*Wg[k*64 + f];
    Hs1[(size_t)row*64 + f] = f2bf(acc * dinv[row]);
    if (f < 10){
      float p = bl[f];
      #pragma unroll
      for (int k = 0; k < 32; k++) p += hr[k]*Wl[k*10 + f];
      atomicMax(&Pool0[batch[row]*10 + f], encf(p));
    }
  }
}

// ---------- shared gather body: acc = sum of Hs rows (8-way unrolled) ----------
__device__ __forceinline__ float gather_sum(const unsigned short* __restrict__ Hs,
    const int* __restrict__ csr, int s, int e, int f){
  float acc = 0.f;
  int j = s;
  for (; j + 7 < e; j += 8){
    const int r0 = csr[j],   r1 = csr[j+1], r2 = csr[j+2], r3 = csr[j+3];
    const int r4 = csr[j+4], r5 = csr[j+5], r6 = csr[j+6], r7 = csr[j+7];
    float t0 = bf2f(Hs[(size_t)r0*64 + f]);
    float t1 = bf2f(Hs[(size_t)r1*64 + f]);
    float t2 = bf2f(Hs[(size_t)r2*64 + f]);
    float t3 = bf2f(Hs[(size_t)r3*64 + f]);
    float t4 = bf2f(Hs[(size_t)r4*64 + f]);
    float t5 = bf2f(Hs[(size_t)r5*64 + f]);
    float t6 = bf2f(Hs[(size_t)r6*64 + f]);
    float t7 = bf2f(Hs[(size_t)r7*64 + f]);
    acc += ((t0 + t1) + (t2 + t3)) + ((t4 + t5) + (t6 + t7));
  }
  for (; j + 3 < e; j += 4){
    const int r0 = csr[j], r1 = csr[j+1], r2 = csr[j+2], r3 = csr[j+3];
    float t0 = bf2f(Hs[(size_t)r0*64 + f]);
    float t1 = bf2f(Hs[(size_t)r1*64 + f]);
    float t2 = bf2f(Hs[(size_t)r2*64 + f]);
    float t3 = bf2f(Hs[(size_t)r3*64 + f]);
    acc += (t0 + t1) + (t2 + t3);
  }
  for (; j < e; j++) acc += bf2f(Hs[(size_t)csr[j]*64 + f]);
  return acc;
}

// ---------- pool epilogue: LDS-combine 4 nodes/block (batch sorted) ----------
__device__ __forceinline__ void pool_epilogue(float h, int w, int f, int c,
    const int* __restrict__ batch, unsigned* __restrict__ Pool,
    float (*sm)[64], int* sb){
  sm[w][f] = h;
  if (f == 0) sb[w] = batch[c];
  __syncthreads();
  if (w == 0){
    const int b0 = sb[0], b1 = sb[1], b2 = sb[2], b3 = sb[3];
    if (b0 == b3){
      float m = fmaxf(fmaxf(sm[0][f], sm[1][f]), fmaxf(sm[2][f], sm[3][f]));
      atomicMax(&Pool[b0*64 + f], encf(m));
    } else {
      atomicMax(&Pool[b0*64 + f], encf(sm[0][f]));
      atomicMax(&Pool[b1*64 + f], encf(sm[1][f]));
      atomicMax(&Pool[b2*64 + f], encf(sm[2][f]));
      atomicMax(&Pool[b3*64 + f], encf(sm[3][f]));
    }
  }
}

// ---------- agg1: h2 = dc*(sum Hs1[r] + Hs1[c]) + bg1; pool; store bf16 h2 ----------
__global__ __launch_bounds__(256) void k_agg1(const unsigned short* __restrict__ Hs,
    const float* __restrict__ dinv, const int* __restrict__ rowstart,
    const int* __restrict__ csr, const float* __restrict__ bias,
    const int* __restrict__ batch, unsigned short* __restrict__ H2b,
    unsigned* __restrict__ Pool){
  __shared__ float sm[4][64];
  __shared__ int sb[4];
  const int w = threadIdx.x >> 6, f = threadIdx.x & 63;
  const int c = blockIdx.x*4 + w;
  const int s = rowstart[c], e = rowstart[c+1];
  float acc = gather_sum(Hs, csr, s, e, f);
  const float dc = dinv[c];
  const float h = fmaf(acc + bf2f(Hs[(size_t)c*64 + f]), dc, bias[f]);
  H2b[(size_t)c*64 + f] = f2bf(h);
  pool_epilogue(h, w, f, c, batch, Pool, sm, sb);
}

// ---------- agg2: h3 = dc*(sum Hs2[r] + Hs2[c]) + bg2; pool only ----------
__global__ __launch_bounds__(256) void k_agg2(const unsigned short* __restrict__ Hs,
    const float* __restrict__ dinv, const int* __restrict__ rowstart,
    const int* __restrict__ csr, const float* __restrict__ bias,
    const int* __restrict__ batch, unsigned* __restrict__ Pool){
  __shared__ float sm[4][64];
  __shared__ int sb[4];
  const int w = threadIdx.x >> 6, f = threadIdx.x & 63;
  const int c = blockIdx.x*4 + w;
  const int s = rowstart[c], e = rowstart[c+1];
  float acc = gather_sum(Hs, csr, s, e, f);
  const float dc = dinv[c];
  const float h = fmaf(acc + bf2f(Hs[(size_t)c*64 + f]), dc, bias[f]);
  pool_epilogue(h, w, f, c, batch, Pool, sm, sb);
}

// ---------- layer1 GEMM: Hs2 = bf16((h2 @ Wg2) * dinv) ----------
__global__ __launch_bounds__(256) void k_layer1(const unsigned short* __restrict__ H2b,
    const float* __restrict__ Wg2, const float* __restrict__ dinv,
    unsigned short* __restrict__ Hs2){
  __shared__ float as[32*68];
  __shared__ float Wg[64*64];
  const int tid = threadIdx.x;
  #pragma unroll
  for (int j = 0; j < 4; j++) ((float4*)Wg)[tid + j*256] = ((const float4*)Wg2)[tid + j*256];
  {
    // 32 rows x 64 bf16 = 2048 ushorts; 8 per thread
    const int rr = tid >> 3, kk = tid & 7;
    ushort4 v0 = ((const ushort4*)H2b)[(size_t)blockIdx.x*512 + tid*2];
    ushort4 v1 = ((const ushort4*)H2b)[(size_t)blockIdx.x*512 + tid*2 + 1];
    float* dst = &as[rr*68 + kk*8];
    dst[0]=bf2f(v0.x); dst[1]=bf2f(v0.y); dst[2]=bf2f(v0.z); dst[3]=bf2f(v0.w);
    dst[4]=bf2f(v1.x); dst[5]=bf2f(v1.y); dst[6]=bf2f(v1.z); dst[7]=bf2f(v1.w);
  }
  __syncthreads();
  const int w = tid >> 6, f = tid & 63;
  for (int i = 0; i < 8; i++){
    const int r = w*8 + i;
    const int row = blockIdx.x*32 + r;
    const float* ar = &as[r*68];
    float acc = 0.f;
    #pragma unroll
    for (int k = 0; k < 64; k++) acc += ar[k]*Wg[k*64 + f];
    Hs2[(size_t)row*64 + f] = f2bf(acc * dinv[row]);
  }
}

// ---------- final: out = P0 + P1@Wl1+bl1 + P2@Wl2+bl2 ----------
__global__ __launch_bounds__(256) void k_final(const unsigned* __restrict__ P0,
    const unsigned* __restrict__ P1, const unsigned* __restrict__ P2,
    const float* __restrict__ Wl1, const float* __restrict__ bl1,
    const float* __restrict__ Wl2, const float* __restrict__ bl2,
    float* __restrict__ out){
  const int t = blockIdx.x*256 + threadIdx.x;
  const int g = t >> 4, c = t & 15;
  if (g >= GG || c >= 10) return;
  float acc = dec0(P0[g*10 + c]) + bl1[c] + bl2[c];
  for (int f = 0; f < 64; f++){
    acc += dec0(P1[g*64 + f]) * Wl1[f*10 + c];
    acc += dec0(P2[g*64 + f]) * Wl2[f*10 + c];
  }
  out[g*10 + c] = acc;
}

extern "C" void kernel_launch(void* const* d_in, const int* in_sizes, int n_in,
                              void* d_out, int out_size, void* d_ws, size_t ws_size,
                              hipStream_t stream){
  const float* x   = (const float*)d_in[0];
  const int*   ei  = (const int*)d_in[1];
  const int*   ew  = (const int*)d_in[2];
  const int*   bat = (const int*)d_in[3];
  const float* W1  = (const float*)d_in[5],  *b1  = (const float*)d_in[6];
  const float* g1  = (const float*)d_in[7],  *bt1 = (const float*)d_in[8];
  const float* W2  = (const float*)d_in[9],  *b2  = (const float*)d_in[10];
  const float* g2  = (const float*)d_in[11], *bt2 = (const float*)d_in[12];
  const float* Wl0 = (const float*)d_in[13], *bl0 = (const float*)d_in[14];
  const float* Wg1 = (const float*)d_in[15], *bg1 = (const float*)d_in[16];
  const float* Wl1 = (const float*)d_in[17], *bl1 = (const float*)d_in[18];
  const float* Wg2 = (const float*)d_in[19], *bg2 = (const float*)d_in[20];
  const float* Wl2 = (const float*)d_in[21], *bl2 = (const float*)d_in[22];

  float* ws = (float*)d_ws;
  // workspace layout (4B elems). Zeroed prefix: cnt | stats | P0 | P1 | P2
  const size_t oCnt   = 0;                         // NN ints
  const size_t oStats = NN;                        // 256
  const size_t oP0    = oStats + 256;              // G*10
  const size_t oP1    = oP0 + (size_t)GG*10;       // G*64
  const size_t oP2    = oP1 + (size_t)GG*64;       // G*64
  const size_t oZEnd  = oP2 + (size_t)GG*64;       // zero prefix end
  const size_t oDinv  = oZEnd;                     // NN
  const size_t oLoc   = oDinv + NN;                // NN
  const size_t oBsum  = oLoc + NN;                 // 512
  const size_t oBoff  = oBsum + 512;               // 512
  const size_t oRS    = oBoff + 512;               // NN+8
  const size_t oFill  = oRS + NN + 8;              // NN
  const size_t oCsr   = oFill + NN;                // EE
  const size_t oA     = oCsr + EE;                 // NN*64 f32 (Y1|Y2), reused: H2b bf16
  const size_t oHs1   = oA + (size_t)NN*64;        // NN*64 bf16 (Hs1, then Hs2)

  int*   cnt   = (int*)(ws + oCnt);
  float* stats = ws + oStats;
  unsigned* P0 = (unsigned*)(ws + oP0);
  unsigned* P1 = (unsigned*)(ws + oP1);
  unsigned* P2 = (unsigned*)(ws + oP2);
  float* dinv  = ws + oDinv;
  int*   loc   = (int*)(ws + oLoc);
  int*   bsum  = (int*)(ws + oBsum);
  int*   boff  = (int*)(ws + oBoff);
  int*   rs    = (int*)(ws + oRS);
  int*   fill  = (int*)(ws + oFill);
  int*   csr   = (int*)(ws + oCsr);
  float* Y1    = ws + oA;
  float* Y2    = ws + oA + (size_t)NN*32;
  unsigned short* H2b = (unsigned short*)(ws + oA);    // reuse Y1 region
  unsigned short* Hs1 = (unsigned short*)(ws + oHs1);  // Hs1, then Hs2 (after agg1 consumed Hs1)
  unsigned short* Hs2 = (unsigned short*)(ws + oA + (size_t)NN*32);  // reuse Y2 region

  (void)hipMemsetAsync(d_ws, 0, oZEnd*sizeof(float), stream);

  // CSR build (shared by both GCN layers)
  k_count  <<<EE/256, 256, 0, stream>>>(ei, ew, cnt);
  k_scan1  <<<NB1, 256, 0, stream>>>(cnt, loc, bsum);
  k_scan2  <<<1, 512, 0, stream>>>(bsum, boff);
  k_fin    <<<NB1, 256, 0, stream>>>(cnt, loc, boff, dinv, rs, fill);
  k_scatter<<<EE/256, 256, 0, stream>>>(ei, ew, fill, csr);

  // MLP + heads
  k_gemm1<<<1536, 256, 0, stream>>>(x, W1, b1, Y1, stats);
  k_mlp2 <<<1536, 256, 0, stream>>>(Y1, W2, b2, g1, bt1, stats, Y2);
  k_layer0<<<3125, 256, 0, stream>>>(Y2, stats, g2, bt2, Wg1, Wl0, bl0, dinv, bat, Hs1, P0);
  k_agg1 <<<NN/4, 256, 0, stream>>>(Hs1, dinv, rs, csr, bg1, bat, H2b, P1);
  k_layer1<<<3125, 256, 0, stream>>>(H2b, Wg2, dinv, Hs2);
  k_agg2 <<<NN/4, 256, 0, stream>>>(Hs2, dinv, rs, csr, bg2, bat, P2);
  k_final<<<(GG*16 + 255)/256, 256, 0, stream>>>(P0, P1, P2, Wl1, bl1, Wl2, bl2, (float*)d_out);
}